// Round 8
// baseline (221.221 us; speedup 1.0000x reference)
//
#include <hip/hip_runtime.h>
#include <math.h>

#define ALPHA 26
#define TPB 256
#define ROWF 26                  // stage row stride in floats (token row)
#define WAVEF (64 * ROWF)        // 1664 floats per wave-private region
#define BUFF (4 * WAVEF)         // 6656 floats per block (single buffer, 26.6 KB)
#define NBLK 2048                // persistent blocks, 2 balanced tiles each

typedef __attribute__((ext_vector_type(8))) short short8;
typedef __attribute__((ext_vector_type(4))) float float4v;

__device__ __forceinline__ unsigned short f2bf(float f) {
    unsigned u = __builtin_bit_cast(unsigned, f);
    u += 0x7FFFu + ((u >> 16) & 1u);          // round-to-nearest-even
    return (unsigned short)(u >> 16);
}

// DPP row_ror:N within each 16-lane row (VALU pipe, no LDS traffic).
template<int CTRL>
__device__ __forceinline__ float rorf(float v) {
    int s = __builtin_bit_cast(int, v);
    int d = __builtin_amdgcn_update_dpp(s, s, CTRL, 0xf, 0xf, false);
    return __builtin_bit_cast(float, d);
}

// Pre-kernel: row-L2-normalize rotor, emit TRANSPOSED bf16 B matrix padded to
// 32x32: rnbT[n][k] = bf16(rotor[k][n]/||rotor[k]||) for k,n<26, else 0.
__global__ void rotor_norm_kernel(const float* __restrict__ rotor,
                                  unsigned short* __restrict__ rnbT) {
    __shared__ float inv[32];
    const int t = threadIdx.x;            // 64 threads
    if (t < 32) {
        float s = 0.f;
        if (t < ALPHA) {
            #pragma unroll
            for (int j = 0; j < ALPHA; ++j) {
                float v = rotor[t * ALPHA + j];
                s += v * v;
            }
            inv[t] = 1.0f / sqrtf(s);
        } else {
            inv[t] = 0.f;
        }
    }
    __syncthreads();
    const int n  = t >> 1;                // 0..31
    const int k0 = (t & 1) * 16;          // 0 or 16
    #pragma unroll
    for (int kk = 0; kk < 16; ++kk) {
        const int k = k0 + kk;
        float v = (k < ALPHA && n < ALPHA) ? rotor[k * ALPHA + n] * inv[k] : 0.f;
        rnbT[n * 32 + k] = f2bf(v);
    }
}

// R7 structure (reg-staged loads -- no global_load_lds, which capped read BW
// at ~2.4 TB/s -- DPP in-register softmax, barrier-free wave-private LDS)
// with the nt stores REMOVED: on gfx950, non-temporal stores bypass L2
// write-combining and amplify HBM writes ~1.8x (R5: 174 MB scattered,
// R7: 195 MB even fully coalesced; plain stores: 106 MB = ideal).
// Per wave-tile LDS traffic: 7 vector stage-in writes + 32 gather reads
// + 32 scatter writes (2-way = free) + 7 vector stage-out reads.
__global__ __launch_bounds__(TPB, 6) void rotor_main(
        const float* __restrict__ x,
        const unsigned short* __restrict__ rnbT,
        float* __restrict__ out,
        int ntiles) {
    __shared__ float stage[BUFF];         // 26624 B -> 6 blocks/CU fit

    const int tid  = threadIdx.x;
    const int lane = tid & 63;
    const int wave = tid >> 6;
    const int n15  = lane & 15;
    const int quad = lane >> 4;
    const int waveF = wave * WAVEF;

    // ---- B fragments: two contiguous 16B loads from transposed rnbT ----
    // B-operand layout (16x16x32): n = lane&15, k = quad*8 + j.
    short8 bf0 = *(const short8*)(rnbT + n15 * 32 + quad * 8);
    short8 bf1 = *(const short8*)(rnbT + (n15 + 16) * 32 + quad * 8);

    int tile = blockIdx.x;
    if (tile >= ntiles) return;
    const int stride = gridDim.x;

    // Per-wave tile slice: 64 tokens x 26 floats = 26 dwords/lane in regs.
    float4 r[6]; float2 r2;
    auto ldregs = [&](int t) {
        const float* gp = x + (long long)t * (TPB * ALPHA) + waveF;
        #pragma unroll
        for (int it = 0; it < 6; ++it)
            r[it] = *(const float4*)(gp + it * 256 + lane * 4);
        r2 = *(const float2*)(gp + 1536 + lane * 2);
    };

    ldregs(tile);

    int i = 0;
    for (; tile < ntiles; tile += stride, ++i) {
        // ---- Stage current tile regs -> LDS (7 vector ds_writes) ----
        {
            float* lp = &stage[waveF];
            #pragma unroll
            for (int it = 0; it < 6; ++it)
                *(float4*)(lp + it * 256 + lane * 4) = r[it];
            *(float2*)(lp + 1536 + lane * 2) = r2;
        }
        const int tnext = tile + stride;
        if (tnext < ntiles) ldregs(tnext);     // T14: issue early, consume at
                                               // next iteration's stage-in

        const int tokBase = tile * TPB + wave * 64;

        // ---- GEMM: 4 M-tiles x 2 N-tiles of mfma_f32_16x16x32_bf16 ----
        float4v accA[4], accB[4];
        #pragma unroll
        for (int m = 0; m < 4; ++m) {
            accA[m] = (float4v){0.f, 0.f, 0.f, 0.f};
            accB[m] = (float4v){0.f, 0.f, 0.f, 0.f};
        }

        #pragma unroll
        for (int m = 0; m < 4; ++m) {
            // A layout: this lane supplies token m*16 + n15, k = quad*8 + j.
            const int tok = tokBase + m * 16 + n15;
            const int r_ = (tok & 8191) % 26;         // S = 8192, position == 1
            const int rowOff = waveF + (m * 16 + n15) * ROWF;
            const int k0 = quad * 8;
            int idx0 = k0 - r_; if (idx0 < 0) idx0 += 26;   // in [0,25]

            short8 af;
            #pragma unroll
            for (int j = 0; j < 8; ++j) {
                int idx = idx0 + j; if (idx >= 26) idx -= 26;  // stays in [0,25]
                // No K-pad mask needed: rnbT rows k>=26 are exact zeros.
                af[j] = (short)f2bf(stage[rowOff + idx]);
            }
            accA[m] = __builtin_amdgcn_mfma_f32_16x16x32_bf16(af, bf0, accA[m], 0, 0, 0);
            accB[m] = __builtin_amdgcn_mfma_f32_16x16x32_bf16(af, bf1, accB[m], 0, 0, 0);
        }

        // ---- In-register softmax (DPP rotate-reduce over the 16-lane row).
        // Lane (n15,quad) holds token m*16+quad*4+rg, features n15 / n15+16.
        // Padded cols 26..31 are exact zeros: excluded from sum; max(real,0)
        // leaves softmax invariant. Scatter results to wave-private LDS
        // (2-way bank aliasing only = free), then stream out coalesced.
        #pragma unroll
        for (int m = 0; m < 4; ++m) {
            #pragma unroll
            for (int rg = 0; rg < 4; ++rg) {
                float a = accA[m][rg];
                float b = accB[m][rg];
                float mx = fmaxf(a, b);
                mx = fmaxf(mx, rorf<0x121>(mx));
                mx = fmaxf(mx, rorf<0x122>(mx));
                mx = fmaxf(mx, rorf<0x124>(mx));
                mx = fmaxf(mx, rorf<0x128>(mx));
                float ea = __expf(a - mx);
                float eb = (n15 < ALPHA - 16) ? __expf(b - mx) : 0.f;
                float s = ea + eb;
                s += rorf<0x121>(s);
                s += rorf<0x122>(s);
                s += rorf<0x124>(s);
                s += rorf<0x128>(s);
                float inv = 1.0f / s;
                const int base = waveF + (m * 16 + quad * 4 + rg) * ROWF;
                stage[base + n15] = ea * inv;
                if (n15 < ALPHA - 16)
                    stage[base + 16 + n15] = eb * inv;
            }
        }

        // ---- Coalesced plain stores (L2-routed: exactly ideal WRITE_SIZE) ----
        float* gout = out + (long long)tile * (TPB * ALPHA) + waveF;
        #pragma unroll
        for (int it = 0; it < 6; ++it) {
            float4 d = *(const float4*)&stage[waveF + it * 256 + lane * 4];
            *(float4*)(gout + it * 256 + lane * 4) = d;
        }
        {
            float2 d = *(const float2*)&stage[waveF + 1536 + lane * 2];
            *(float2*)(gout + 1536 + lane * 2) = d;
        }
    }
}

extern "C" void kernel_launch(void* const* d_in, const int* in_sizes, int n_in,
                              void* d_out, int out_size, void* d_ws, size_t ws_size,
                              hipStream_t stream) {
    const float* x     = (const float*)d_in[0];   // [128, 8192, 26] fp32
    const float* rotor = (const float*)d_in[1];   // [26, 26] fp32
    float* out = (float*)d_out;                   // [128, 8192, 26] fp32
    unsigned short* rnbT = (unsigned short*)d_ws; // bf16 B^T matrix, 32x32 = 2 KB

    rotor_norm_kernel<<<1, 64, 0, stream>>>(rotor, rnbT);

    const int tokens = out_size / ALPHA;          // 1,048,576
    const int tiles  = tokens / TPB;              // 4096
    const int grid   = (tiles < NBLK) ? tiles : NBLK;
    rotor_main<<<grid, TPB, 0, stream>>>(x, rnbT, out, tiles);
}